// Round 1
// baseline (385.800 us; speedup 1.0000x reference)
//
#include <hip/hip_runtime.h>
#include <math.h>

// Problem constants
#define NBATCH 4
#define NCLS   19
#define HWDIM  512
#define HW     (512 * 512)      // 262144
#define PH     171              // pooled H=W
#define PP2    (171 * 171)      // 29241
#define NHW    169              // PH - radius + 1
#define MM     (169 * 169)      // 28561

// ---------------------------------------------------------------------------
// Stage 1: fused softmax + one-hot + 3x3/stride-3 avg-pool (pad=1, /9 always)
// One thread per pooled output pixel (n, ph, pw); writes pooled probs P and
// pooled one-hot L, each (N, C, 171, 171) f32.
// ---------------------------------------------------------------------------
__global__ __launch_bounds__(256) void stage1_pool(
    const float* __restrict__ cls, const int* __restrict__ label,
    float* __restrict__ P, float* __restrict__ L) {
  int idx = blockIdx.x * 256 + threadIdx.x;
  if (idx >= NBATCH * PP2) return;
  int n   = idx / PP2;
  int rem = idx - n * PP2;
  int ph  = rem / PH;
  int pw  = rem - ph * PH;

  float accP[NCLS], accL[NCLS];
#pragma unroll
  for (int c = 0; c < NCLS; ++c) { accP[c] = 0.f; accL[c] = 0.f; }

#pragma unroll
  for (int i = 0; i < 3; ++i) {
    int r = 3 * ph - 1 + i;
    if (r < 0 || r >= HWDIM) continue;
#pragma unroll
    for (int j = 0; j < 3; ++j) {
      int q = 3 * pw - 1 + j;
      if (q < 0 || q >= HWDIM) continue;
      int lb = label[((size_t)n * HWDIM + r) * HWDIM + q];
      const float* base = cls + (size_t)n * NCLS * HW + (size_t)r * HWDIM + q;
      float v[NCLS];
      float mx = -INFINITY;
#pragma unroll
      for (int c = 0; c < NCLS; ++c) {
        v[c] = base[(size_t)c * HW];
        mx = fmaxf(mx, v[c]);
      }
      float se = 0.f;
#pragma unroll
      for (int c = 0; c < NCLS; ++c) {
        v[c] = expf(v[c] - mx);
        se += v[c];
      }
      // valid = (lb>=0 && lb<19); 255 check subsumed. Invalid pixels zero
      // BOTH probs and onehot (vmask multiplies both in the reference).
      if (lb >= 0 && lb < NCLS) {
        float inv = 1.f / se;
#pragma unroll
        for (int c = 0; c < NCLS; ++c) {
          accP[c] += v[c] * inv;
          accL[c] += (lb == c) ? 1.f : 0.f;  // compile-time index (no scratch)
        }
      }
    }
  }

  size_t o = (size_t)n * NCLS * PP2 + (size_t)ph * PH + pw;
  const float inv9 = 1.f / 9.f;
#pragma unroll
  for (int c = 0; c < NCLS; ++c) {
    P[o + (size_t)c * PP2] = accP[c] * inv9;
    L[o + (size_t)c * PP2] = accL[c] * inv9;
  }
}

// ---------------------------------------------------------------------------
// Stage 2: per (n,c) raw-moment accumulation over M=169^2 positions.
// Moment layout per (n,c), stride 192 floats:
//   [0..8]   = sum la[d]
//   [9..17]  = sum pr[d]
//   [18..62] = sum la[d]*la[e],  d<=e (45, row-major upper-tri)
//   [63..107]= sum pr[d]*pr[e],  d<=e (45)
//   [108..188]= sum pr[d]*la[e]  (81, d*9+e)
// PART 0 -> first 63, PART 1 -> PP 45, PART 2 -> PL 81 (register-pressure split)
// ---------------------------------------------------------------------------
template <int PART>
__global__ __launch_bounds__(256) void stage2_mom(
    const float* __restrict__ P, const float* __restrict__ L,
    float* __restrict__ cov) {
  constexpr int NA  = (PART == 0) ? 63 : (PART == 1 ? 45 : 81);
  constexpr int OFF = (PART == 0) ? 0  : (PART == 1 ? 63 : 108);
  int nc = blockIdx.x;
  const float* Pp = P + (size_t)nc * PP2;
  const float* Lp = L + (size_t)nc * PP2;

  float acc[NA];
#pragma unroll
  for (int k = 0; k < NA; ++k) acc[k] = 0.f;

  for (int m = threadIdx.x; m < MM; m += 256) {
    int yy = m / NHW;
    int xx = m - yy * NHW;
    int base = yy * PH + xx;
    float la[9], pr[9];
#pragma unroll
    for (int dy = 0; dy < 3; ++dy) {
#pragma unroll
      for (int dx = 0; dx < 3; ++dx) {
        int d = dy * 3 + dx;
        pr[d] = Pp[base + dy * PH + dx];
        if (PART != 1) la[d] = Lp[base + dy * PH + dx];
      }
    }
    if (PART == 0) {
#pragma unroll
      for (int d = 0; d < 9; ++d) {
        acc[d]     += la[d];
        acc[9 + d] += pr[d];
      }
      int k = 18;
#pragma unroll
      for (int d = 0; d < 9; ++d)
#pragma unroll
        for (int e = d; e < 9; ++e) { acc[k] += la[d] * la[e]; ++k; }
    } else if (PART == 1) {
      int k = 0;
#pragma unroll
      for (int d = 0; d < 9; ++d)
#pragma unroll
        for (int e = d; e < 9; ++e) { acc[k] += pr[d] * pr[e]; ++k; }
    } else {
#pragma unroll
      for (int d = 0; d < 9; ++d)
#pragma unroll
        for (int e = 0; e < 9; ++e) acc[d * 9 + e] += pr[d] * la[e];
    }
  }

  // wave shuffle-reduce (wave = 64) then cross-wave via LDS
  __shared__ float red[4 * 81];
  int lane = threadIdx.x & 63;
  int wid  = threadIdx.x >> 6;
#pragma unroll
  for (int k = 0; k < NA; ++k) {
    float v = acc[k];
#pragma unroll
    for (int o = 32; o > 0; o >>= 1) v += __shfl_down(v, o, 64);
    if (lane == 0) red[wid * NA + k] = v;
  }
  __syncthreads();
  if (threadIdx.x < NA) {
    float s = red[threadIdx.x] + red[NA + threadIdx.x] +
              red[2 * NA + threadIdx.x] + red[3 * NA + threadIdx.x];
    cov[(size_t)nc * 192 + OFF + threadIdx.x] = s;
  }
}

// ---------------------------------------------------------------------------
// Stage 3: 76 threads; each builds covariances in fp64, inverts la_cov+1e-5 I,
// forms the Schur complement + 1e-6 I, Cholesky logdet; block-reduces the sum.
// total = sum_{n,c} 0.5*logdet / (N*NUM_CLASSES)
// ---------------------------------------------------------------------------
__global__ __launch_bounds__(128) void stage3_rmi(
    const float* __restrict__ cov, float* __restrict__ out) {
  __shared__ double red[128];
  int tid = threadIdx.x;
  double val = 0.0;
  if (tid < NBATCH * NCLS) {
    const float* s = cov + (size_t)tid * 192;
    const double Minv = 1.0 / (double)MM;
    double mla[9], mpr[9];
    for (int d = 0; d < 9; ++d) { mla[d] = s[d] * Minv; mpr[d] = s[9 + d] * Minv; }
    double lc[81], pc[81], plc[81];
    {
      int k = 0;
      for (int d = 0; d < 9; ++d)
        for (int e = d; e < 9; ++e) {
          double a = (double)s[18 + k] * Minv - mla[d] * mla[e];
          lc[d * 9 + e] = a; lc[e * 9 + d] = a;
          double b = (double)s[63 + k] * Minv - mpr[d] * mpr[e];
          pc[d * 9 + e] = b; pc[e * 9 + d] = b;
          ++k;
        }
      for (int d = 0; d < 9; ++d)
        for (int e = 0; e < 9; ++e)
          plc[d * 9 + e] = (double)s[108 + d * 9 + e] * Minv - mpr[d] * mla[e];
    }
    for (int d = 0; d < 9; ++d) lc[d * 9 + d] += 1e-5;

    // Gauss-Jordan inverse of lc (partial pivoting)
    double aug[9][18];
    for (int r = 0; r < 9; ++r)
      for (int c = 0; c < 9; ++c) {
        aug[r][c] = lc[r * 9 + c];
        aug[r][9 + c] = (r == c) ? 1.0 : 0.0;
      }
    for (int col = 0; col < 9; ++col) {
      int piv = col; double best = fabs(aug[col][col]);
      for (int r = col + 1; r < 9; ++r) {
        double a = fabs(aug[r][col]);
        if (a > best) { best = a; piv = r; }
      }
      if (piv != col)
        for (int j = 0; j < 18; ++j) {
          double t = aug[col][j]; aug[col][j] = aug[piv][j]; aug[piv][j] = t;
        }
      double ip = 1.0 / aug[col][col];
      for (int j = 0; j < 18; ++j) aug[col][j] *= ip;
      for (int r = 0; r < 9; ++r) {
        if (r == col) continue;
        double f = aug[r][col];
        for (int j = 0; j < 18; ++j) aug[r][j] -= f * aug[col][j];
      }
    }

    // T = plc @ inv ; A = pc - T @ plc^T + 1e-6 I
    double T[81];
    for (int d = 0; d < 9; ++d)
      for (int f = 0; f < 9; ++f) {
        double acc2 = 0.0;
        for (int e = 0; e < 9; ++e) acc2 += plc[d * 9 + e] * aug[e][9 + f];
        T[d * 9 + f] = acc2;
      }
    double A[81];
    for (int d = 0; d < 9; ++d)
      for (int g = 0; g < 9; ++g) {
        double acc2 = 0.0;
        for (int f = 0; f < 9; ++f) acc2 += T[d * 9 + f] * plc[g * 9 + f];
        A[d * 9 + g] = pc[d * 9 + g] - acc2;
      }
    for (int d = 0; d < 9; ++d) A[d * 9 + d] += 1e-6;

    // Cholesky (lower) + logdet = 2 * sum log(L_jj + 1e-8)
    double Lm[81];
    double sumlog = 0.0;
    for (int j = 0; j < 9; ++j) {
      double dv = A[j * 9 + j];
      for (int k = 0; k < j; ++k) dv -= Lm[j * 9 + k] * Lm[j * 9 + k];
      double ljj = sqrt(dv);
      Lm[j * 9 + j] = ljj;
      sumlog += log(ljj + 1e-8);
      double il = 1.0 / ljj;
      for (int i2 = j + 1; i2 < 9; ++i2) {
        double t = A[i2 * 9 + j];
        for (int k = 0; k < j; ++k) t -= Lm[i2 * 9 + k] * Lm[j * 9 + k];
        Lm[i2 * 9 + j] = t * il;
      }
    }
    // rmi_{n,c} = 0.5 * (2*sumlog) = sumlog ; total = sum / (N*NUM_CLASSES)
    val = sumlog / (double)(NBATCH * NCLS);
  }
  red[tid] = val;
  __syncthreads();
  for (int st = 64; st > 0; st >>= 1) {
    if (tid < st) red[tid] += red[tid + st];
    __syncthreads();
  }
  if (tid == 0) out[0] = (float)red[0];
}

// ---------------------------------------------------------------------------
extern "C" void kernel_launch(void* const* d_in, const int* in_sizes, int n_in,
                              void* d_out, int out_size, void* d_ws, size_t ws_size,
                              hipStream_t stream) {
  const float* cls  = (const float*)d_in[0];
  const int* label  = (const int*)d_in[1];
  float* out = (float*)d_out;

  float* P   = (float*)d_ws;                              // 4*19*29241 f32
  float* L   = P + (size_t)NBATCH * NCLS * PP2;           // 4*19*29241 f32
  float* cov = L + (size_t)NBATCH * NCLS * PP2;           // 76*192 f32

  int total = NBATCH * PP2;
  stage1_pool<<<(total + 255) / 256, 256, 0, stream>>>(cls, label, P, L);
  stage2_mom<0><<<NBATCH * NCLS, 256, 0, stream>>>(P, L, cov);
  stage2_mom<1><<<NBATCH * NCLS, 256, 0, stream>>>(P, L, cov);
  stage2_mom<2><<<NBATCH * NCLS, 256, 0, stream>>>(P, L, cov);
  stage3_rmi<<<1, 128, 0, stream>>>(cov, out);
}

// Round 2
// 92.643 us; speedup vs baseline: 4.1644x; 4.1644x over previous
//
#include <hip/hip_runtime.h>
#include <math.h>

// Problem constants
#define NBATCH 4
#define NCLS   19
#define HWDIM  512
#define HW     (512 * 512)      // 262144
#define PH     171              // pooled H=W
#define PP2    (171 * 171)      // 29241
#define NHW    169              // PH - radius + 1
#define MM     (169 * 169)      // 28561

// ---------------------------------------------------------------------------
// Stage 1: fused softmax + one-hot + 3x3/stride-3 avg-pool (pad=1, /9 always)
// One thread per pooled output pixel (n, ph, pw); writes pooled probs P and
// pooled one-hot L, each (N, C, 171, 171) f32.
// ---------------------------------------------------------------------------
__global__ __launch_bounds__(256) void stage1_pool(
    const float* __restrict__ cls, const int* __restrict__ label,
    float* __restrict__ P, float* __restrict__ L) {
  int idx = blockIdx.x * 256 + threadIdx.x;
  if (idx >= NBATCH * PP2) return;
  int n   = idx / PP2;
  int rem = idx - n * PP2;
  int ph  = rem / PH;
  int pw  = rem - ph * PH;

  float accP[NCLS], accL[NCLS];
#pragma unroll
  for (int c = 0; c < NCLS; ++c) { accP[c] = 0.f; accL[c] = 0.f; }

#pragma unroll
  for (int i = 0; i < 3; ++i) {
    int r = 3 * ph - 1 + i;
    if (r < 0 || r >= HWDIM) continue;
#pragma unroll
    for (int j = 0; j < 3; ++j) {
      int q = 3 * pw - 1 + j;
      if (q < 0 || q >= HWDIM) continue;
      int lb = label[((size_t)n * HWDIM + r) * HWDIM + q];
      const float* base = cls + (size_t)n * NCLS * HW + (size_t)r * HWDIM + q;
      float v[NCLS];
      float mx = -INFINITY;
#pragma unroll
      for (int c = 0; c < NCLS; ++c) {
        v[c] = base[(size_t)c * HW];
        mx = fmaxf(mx, v[c]);
      }
      float se = 0.f;
#pragma unroll
      for (int c = 0; c < NCLS; ++c) {
        v[c] = expf(v[c] - mx);
        se += v[c];
      }
      if (lb >= 0 && lb < NCLS) {
        float inv = 1.f / se;
#pragma unroll
        for (int c = 0; c < NCLS; ++c) {
          accP[c] += v[c] * inv;
          accL[c] += (lb == c) ? 1.f : 0.f;
        }
      }
    }
  }

  size_t o = (size_t)n * NCLS * PP2 + (size_t)ph * PH + pw;
  const float inv9 = 1.f / 9.f;
#pragma unroll
  for (int c = 0; c < NCLS; ++c) {
    P[o + (size_t)c * PP2] = accP[c] * inv9;
    L[o + (size_t)c * PP2] = accL[c] * inv9;
  }
}

// ---------------------------------------------------------------------------
// Stage 2: per (n,c) raw-moment accumulation over M=169^2 positions.
// Moment layout per (n,c), stride 192 floats:
//   [0..8]    sum la[d]
//   [9..17]   sum pr[d]
//   [18..62]  sum la[d]*la[e],  d<=e (45 upper-tri)
//   [63..107] sum pr[d]*pr[e],  d<=e (45)
//   [108..188] sum pr[d]*la[e]  (81, d*9+e)
//   [190..191] (as double) per-nc logdet result written by stage3
// Grid (76, 3): blockIdx.y selects the accumulator subset (reg pressure).
// ---------------------------------------------------------------------------
template <int PART>
__device__ __forceinline__ void mom_body(
    int nc, const float* __restrict__ P, const float* __restrict__ L,
    float* __restrict__ cov, float* red) {
  constexpr int NA  = (PART == 0) ? 63 : (PART == 1 ? 45 : 81);
  constexpr int OFF = (PART == 0) ? 0  : (PART == 1 ? 63 : 108);
  const float* Pp = P + (size_t)nc * PP2;
  const float* Lp = L + (size_t)nc * PP2;

  float acc[NA];
#pragma unroll
  for (int k = 0; k < NA; ++k) acc[k] = 0.f;

  for (int m = threadIdx.x; m < MM; m += 512) {
    int yy = m / NHW;
    int xx = m - yy * NHW;
    int base = yy * PH + xx;
    float la[9], pr[9];
#pragma unroll
    for (int dy = 0; dy < 3; ++dy) {
#pragma unroll
      for (int dx = 0; dx < 3; ++dx) {
        int d = dy * 3 + dx;
        pr[d] = Pp[base + dy * PH + dx];
        if (PART != 1) la[d] = Lp[base + dy * PH + dx];
      }
    }
    if (PART == 0) {
#pragma unroll
      for (int d = 0; d < 9; ++d) {
        acc[d]     += la[d];
        acc[9 + d] += pr[d];
      }
      int k = 18;
#pragma unroll
      for (int d = 0; d < 9; ++d)
#pragma unroll
        for (int e = d; e < 9; ++e) { acc[k] += la[d] * la[e]; ++k; }
    } else if (PART == 1) {
      int k = 0;
#pragma unroll
      for (int d = 0; d < 9; ++d)
#pragma unroll
        for (int e = d; e < 9; ++e) { acc[k] += pr[d] * pr[e]; ++k; }
    } else {
#pragma unroll
      for (int d = 0; d < 9; ++d)
#pragma unroll
        for (int e = 0; e < 9; ++e) acc[d * 9 + e] += pr[d] * la[e];
    }
  }

  int lane = threadIdx.x & 63;
  int wid  = threadIdx.x >> 6;   // 8 waves
#pragma unroll
  for (int k = 0; k < NA; ++k) {
    float v = acc[k];
#pragma unroll
    for (int o = 32; o > 0; o >>= 1) v += __shfl_down(v, o, 64);
    if (lane == 0) red[wid * NA + k] = v;
  }
  __syncthreads();
  if (threadIdx.x < NA) {
    float s = 0.f;
#pragma unroll
    for (int w = 0; w < 8; ++w) s += red[w * NA + threadIdx.x];
    cov[(size_t)nc * 192 + OFF + threadIdx.x] = s;
  }
}

__global__ __launch_bounds__(512) void stage2_mom(
    const float* __restrict__ P, const float* __restrict__ L,
    float* __restrict__ cov) {
  __shared__ float red[8 * 81];
  int nc = blockIdx.x;
  if (blockIdx.y == 0)      mom_body<0>(nc, P, L, cov, red);
  else if (blockIdx.y == 1) mom_body<1>(nc, P, L, cov, red);
  else                      mom_body<2>(nc, P, L, cov, red);
}

// ---------------------------------------------------------------------------
// Stage 3: one 64-thread block per (n,c). All matrices in LDS (fp64).
//   lc  = la_cov + 1e-5 I  -> Cholesky L1 (lower, in place)
//   W   = plc * L1^{-T}    (triangular solve, row-parallel, in place in plc)
//   A   = pc - W W^T + 1e-6 I -> Cholesky -> sum log(diag + 1e-8)
// Writes per-nc fp64 result into cov[nc*192 + 190..191].
// ---------------------------------------------------------------------------
__global__ __launch_bounds__(64) void stage3_rmi(float* __restrict__ cov) {
  int nc  = blockIdx.x;
  int tid = threadIdx.x;
  const float* s = cov + (size_t)nc * 192;
  __shared__ double lc[81], pc[81], plc[81], mla[9], mpr[9];
  const double Minv = 1.0 / (double)MM;

  if (tid < 9)       mla[tid]     = (double)s[tid] * Minv;
  else if (tid < 18) mpr[tid - 9] = (double)s[tid] * Minv;
  __syncthreads();

  for (int e = tid; e < 81; e += 64) {
    int r = e / 9, c = e - 9 * (e / 9);
    int lo = r < c ? r : c, hi = r < c ? c : r;
    int k = lo * 9 - lo * (lo - 1) / 2 + (hi - lo);
    double a = (double)s[18 + k] * Minv - mla[r] * mla[c];
    if (r == c) a += 1e-5;
    lc[e] = a;
    pc[e] = (double)s[63 + k] * Minv - mpr[r] * mpr[c];
    plc[e] = (double)s[108 + e] * Minv - mpr[r] * mla[c];
  }
  __syncthreads();

  // Cholesky of lc (lower triangle), column-by-column
  for (int j = 0; j < 9; ++j) {
    if (tid == 0) lc[j * 9 + j] = sqrt(lc[j * 9 + j]);
    __syncthreads();
    if (tid > j && tid < 9) lc[tid * 9 + j] /= lc[j * 9 + j];
    __syncthreads();
    if (tid > j && tid < 9) {
      double lij = lc[tid * 9 + j];
      for (int k = j + 1; k <= tid; ++k) lc[tid * 9 + k] -= lij * lc[k * 9 + j];
    }
    __syncthreads();
  }

  // Solve W * L1^T = plc  (row d per lane, forward in j), in place
  if (tid < 9) {
    int d = tid;
    for (int j = 0; j < 9; ++j) {
      double t = plc[d * 9 + j];
      for (int k = 0; k < j; ++k) t -= plc[d * 9 + k] * lc[j * 9 + k];
      plc[d * 9 + j] = t / lc[j * 9 + j];
    }
  }
  __syncthreads();

  // A = pc - W W^T + 1e-6 I  (in place in pc)
  for (int e = tid; e < 81; e += 64) {
    int r = e / 9, c = e - 9 * (e / 9);
    double a = pc[e];
    for (int f = 0; f < 9; ++f) a -= plc[r * 9 + f] * plc[c * 9 + f];
    if (r == c) a += 1e-6;
    pc[e] = a;
  }
  __syncthreads();

  // Cholesky of pc
  for (int j = 0; j < 9; ++j) {
    if (tid == 0) pc[j * 9 + j] = sqrt(pc[j * 9 + j]);
    __syncthreads();
    if (tid > j && tid < 9) pc[tid * 9 + j] /= pc[j * 9 + j];
    __syncthreads();
    if (tid > j && tid < 9) {
      double lij = pc[tid * 9 + j];
      for (int k = j + 1; k <= tid; ++k) pc[tid * 9 + k] -= lij * pc[k * 9 + j];
    }
    __syncthreads();
  }

  if (tid == 0) {
    double sl = 0.0;
    for (int j = 0; j < 9; ++j) sl += log(pc[j * 9 + j] + 1e-8);
    // rmi_{n,c} = 0.5 * (2 * sl) = sl
    *(double*)(cov + (size_t)nc * 192 + 190) = sl;
  }
}

// ---------------------------------------------------------------------------
// Stage 4: reduce 76 fp64 partials -> out[0] = sum / (N * NUM_CLASSES)
// ---------------------------------------------------------------------------
__global__ __launch_bounds__(64) void stage4_reduce(
    const float* __restrict__ cov, float* __restrict__ out) {
  int tid = threadIdx.x;
  double v = 0.0;
  if (tid < NBATCH * NCLS)
    v = *(const double*)(cov + (size_t)tid * 192 + 190);
  if (tid + 64 < NBATCH * NCLS)
    v += *(const double*)(cov + (size_t)(tid + 64) * 192 + 190);
#pragma unroll
  for (int o = 32; o > 0; o >>= 1) v += __shfl_down(v, o, 64);
  if (tid == 0) out[0] = (float)(v / (double)(NBATCH * NCLS));
}

// ---------------------------------------------------------------------------
extern "C" void kernel_launch(void* const* d_in, const int* in_sizes, int n_in,
                              void* d_out, int out_size, void* d_ws, size_t ws_size,
                              hipStream_t stream) {
  const float* cls  = (const float*)d_in[0];
  const int* label  = (const int*)d_in[1];
  float* out = (float*)d_out;

  float* P   = (float*)d_ws;                              // 4*19*29241 f32
  float* L   = P + (size_t)NBATCH * NCLS * PP2;           // 4*19*29241 f32
  float* cov = L + (size_t)NBATCH * NCLS * PP2;           // 76*192 f32

  int total = NBATCH * PP2;
  stage1_pool<<<(total + 255) / 256, 256, 0, stream>>>(cls, label, P, L);
  dim3 g2(NBATCH * NCLS, 3, 1);
  stage2_mom<<<g2, 512, 0, stream>>>(P, L, cov);
  stage3_rmi<<<NBATCH * NCLS, 64, 0, stream>>>(cov);
  stage4_reduce<<<1, 64, 0, stream>>>(cov, out);
}

// Round 3
// 80.441 us; speedup vs baseline: 4.7960x; 1.1517x over previous
//
#include <hip/hip_runtime.h>
#include <math.h>

// Problem constants
#define NBATCH 4
#define NCLS   19
#define HWDIM  512
#define HW     (512 * 512)      // 262144
#define PH     171              // pooled H=W
#define PP2    (171 * 171)      // 29241
#define NHW    169              // PH - radius + 1
#define MM     (169 * 169)      // 28561
#define ZSPLIT 2                // stage2 row-split

// ---------------------------------------------------------------------------
// Stage 1: fused softmax + one-hot + 3x3/stride-3 avg-pool (pad=1, /9 always).
// One block per (n, pooled-row ph); thread = input column (512 threads).
// Class-plane loads are perfectly coalesced (lane stride 4B). y-pool in
// registers; x-pool (cols 3pw-1..3pw+1) via LDS, 4 classes per sync round.
// ---------------------------------------------------------------------------
__global__ __launch_bounds__(512) void stage1_pool(
    const float* __restrict__ cls, const int* __restrict__ label,
    float* __restrict__ P, float* __restrict__ L) {
  int n  = blockIdx.x / PH;
  int ph = blockIdx.x - n * PH;
  int col = threadIdx.x;  // input column 0..511

  float accP[NCLS], accL[NCLS];
#pragma unroll
  for (int c = 0; c < NCLS; ++c) { accP[c] = 0.f; accL[c] = 0.f; }

#pragma unroll
  for (int i = 0; i < 3; ++i) {
    int r = 3 * ph - 1 + i;
    if (r < 0 || r >= HWDIM) continue;
    int lb = label[((size_t)n * HWDIM + r) * HWDIM + col];
    const float* base = cls + (size_t)n * NCLS * HW + (size_t)r * HWDIM + col;
    float v[NCLS];
    float mx = -INFINITY;
#pragma unroll
    for (int c = 0; c < NCLS; ++c) {
      v[c] = base[(size_t)c * HW];
      mx = fmaxf(mx, v[c]);
    }
    float se = 0.f;
#pragma unroll
    for (int c = 0; c < NCLS; ++c) {
      v[c] = expf(v[c] - mx);
      se += v[c];
    }
    // valid = (lb>=0 && lb<19); invalid zeroes BOTH probs and onehot.
    if (lb >= 0 && lb < NCLS) {
      float inv = 1.f / se;
#pragma unroll
      for (int c = 0; c < NCLS; ++c) {
        accP[c] += v[c] * inv;
        accL[c] += (lb == c) ? 1.f : 0.f;  // compile-time index
      }
    }
  }

  // x-pool: xb[cc][1+q] = column q accumulator; xb[cc][0] = left pad (zero).
  __shared__ float xbP[4][516];
  __shared__ float xbL[4][516];
  const float inv9 = 1.f / 9.f;
#pragma unroll
  for (int c0 = 0; c0 < NCLS; c0 += 4) {
    int nc_round = (NCLS - c0) < 4 ? (NCLS - c0) : 4;
#pragma unroll
    for (int cc = 0; cc < 4; ++cc) {
      if (cc < nc_round) {
        xbP[cc][1 + col] = accP[(c0 + cc) < NCLS ? (c0 + cc) : 0];
        xbL[cc][1 + col] = accL[(c0 + cc) < NCLS ? (c0 + cc) : 0];
        if (col == 0) { xbP[cc][0] = 0.f; xbL[cc][0] = 0.f; }
      }
    }
    __syncthreads();
    if (col < PH) {
      int pw = col;
#pragma unroll
      for (int cc = 0; cc < 4; ++cc) {
        if (cc < nc_round) {
          int c = c0 + cc;
          float sP = xbP[cc][3 * pw] + xbP[cc][3 * pw + 1] + xbP[cc][3 * pw + 2];
          float sL = xbL[cc][3 * pw] + xbL[cc][3 * pw + 1] + xbL[cc][3 * pw + 2];
          size_t o = ((size_t)(n * NCLS + c)) * PP2 + (size_t)ph * PH + pw;
          P[o] = sP * inv9;
          L[o] = sL * inv9;
        }
      }
    }
    __syncthreads();
  }
}

// ---------------------------------------------------------------------------
// Stage 2: per (n,c) raw-moment accumulation over M=169^2 window positions,
// sliding-window in y: thread owns column xx, loads only 3 new contiguous
// floats per plane per step. Grid (76, 3 parts, ZSPLIT row-halves).
// Moment layout per (z,nc) record, stride 192 floats:
//   [0..8] sum la | [9..17] sum pr | [18..62] la*la ut45 | [63..107] pr*pr ut45
//   [108..188] pr[d]*la[e] (81) | [190..191] (double) logdet (z=0 only)
// ---------------------------------------------------------------------------
template <int PART>
__device__ __forceinline__ void mom_body(
    int nc, int z, const float* __restrict__ P, const float* __restrict__ L,
    float* __restrict__ covp, float* red) {
  constexpr int NA  = (PART == 0) ? 63 : (PART == 1 ? 45 : 81);
  constexpr int OFF = (PART == 0) ? 0  : (PART == 1 ? 63 : 108);
  const float* Pp = P + (size_t)nc * PP2;
  const float* Lp = L + (size_t)nc * PP2;

  float acc[NA];
#pragma unroll
  for (int k = 0; k < NA; ++k) acc[k] = 0.f;

  int task = threadIdx.x;  // 507 tasks: (xx, ysub)
  if (task < 3 * NHW) {
    int ysub = task / NHW;
    int xx   = task - ysub * NHW;
    int base = z * 85;
    int rt   = (z == 0) ? 85 : (NHW - 85);  // rows in this z-half
    int y0 = base + (rt * ysub) / 3;
    int y1 = base + (rt * (ysub + 1)) / 3;

    float wp[9], wl[9];
    // prime rows y0, y0+1 -> window slots 0..5
#pragma unroll
    for (int dy = 0; dy < 2; ++dy) {
#pragma unroll
      for (int dx = 0; dx < 3; ++dx) {
        wp[dy * 3 + dx] = Pp[(y0 + dy) * PH + xx + dx];
        if (PART != 1) wl[dy * 3 + dx] = Lp[(y0 + dy) * PH + xx + dx];
      }
    }
    for (int y = y0; y < y1; ++y) {
#pragma unroll
      for (int dx = 0; dx < 3; ++dx) {
        wp[6 + dx] = Pp[(y + 2) * PH + xx + dx];
        if (PART != 1) wl[6 + dx] = Lp[(y + 2) * PH + xx + dx];
      }
      if (PART == 0) {
#pragma unroll
        for (int d = 0; d < 9; ++d) {
          acc[d]     += wl[d];
          acc[9 + d] += wp[d];
        }
        int k = 18;
#pragma unroll
        for (int d = 0; d < 9; ++d)
#pragma unroll
          for (int e = d; e < 9; ++e) { acc[k] += wl[d] * wl[e]; ++k; }
      } else if (PART == 1) {
        int k = 0;
#pragma unroll
        for (int d = 0; d < 9; ++d)
#pragma unroll
          for (int e = d; e < 9; ++e) { acc[k] += wp[d] * wp[e]; ++k; }
      } else {
#pragma unroll
        for (int d = 0; d < 9; ++d)
#pragma unroll
          for (int e = 0; e < 9; ++e) acc[d * 9 + e] += wp[d] * wl[e];
      }
      // shift window up one row (static indices)
#pragma unroll
      for (int t = 0; t < 6; ++t) {
        wp[t] = wp[t + 3];
        if (PART != 1) wl[t] = wl[t + 3];
      }
    }
  }

  int lane = threadIdx.x & 63;
  int wid  = threadIdx.x >> 6;  // 8 waves
#pragma unroll
  for (int k = 0; k < NA; ++k) {
    float v = acc[k];
#pragma unroll
    for (int o = 32; o > 0; o >>= 1) v += __shfl_down(v, o, 64);
    if (lane == 0) red[wid * NA + k] = v;
  }
  __syncthreads();
  if (threadIdx.x < NA) {
    float s = 0.f;
#pragma unroll
    for (int w = 0; w < 8; ++w) s += red[w * NA + threadIdx.x];
    covp[((size_t)z * NBATCH * NCLS + nc) * 192 + OFF + threadIdx.x] = s;
  }
}

__global__ __launch_bounds__(512) void stage2_mom(
    const float* __restrict__ P, const float* __restrict__ L,
    float* __restrict__ covp) {
  __shared__ float red[8 * 81];
  int nc = blockIdx.x;
  int z  = blockIdx.z;
  if (blockIdx.y == 0)      mom_body<0>(nc, z, P, L, covp, red);
  else if (blockIdx.y == 1) mom_body<1>(nc, z, P, L, covp, red);
  else                      mom_body<2>(nc, z, P, L, covp, red);
}

// ---------------------------------------------------------------------------
// Stage 3: one 64-thread block per (n,c). Sums the ZSPLIT partials, builds
// covariances in fp64 in LDS, Cholesky(la_cov+1e-5 I), triangular solve,
// Schur complement + 1e-6 I, Cholesky logdet. Result -> covp[nc*192+190..191].
// ---------------------------------------------------------------------------
__global__ __launch_bounds__(64) void stage3_rmi(float* __restrict__ covp) {
  int nc  = blockIdx.x;
  int tid = threadIdx.x;
  const float* s0 = covp + (size_t)nc * 192;
  const float* s1 = covp + ((size_t)NBATCH * NCLS + nc) * 192;
  __shared__ double lc[81], pc[81], plc[81], mla[9], mpr[9];
  const double Minv = 1.0 / (double)MM;
#define LDM(k) ((double)s0[k] + (double)s1[k])

  if (tid < 9)       mla[tid]     = LDM(tid) * Minv;
  else if (tid < 18) mpr[tid - 9] = LDM(tid) * Minv;
  __syncthreads();

  for (int e = tid; e < 81; e += 64) {
    int r = e / 9, c = e - 9 * (e / 9);
    int lo = r < c ? r : c, hi = r < c ? c : r;
    int k = lo * 9 - lo * (lo - 1) / 2 + (hi - lo);
    double a = LDM(18 + k) * Minv - mla[r] * mla[c];
    if (r == c) a += 1e-5;
    lc[e] = a;
    pc[e] = LDM(63 + k) * Minv - mpr[r] * mpr[c];
    plc[e] = LDM(108 + e) * Minv - mpr[r] * mla[c];
  }
  __syncthreads();

  // Cholesky of lc (lower), column-by-column
  for (int j = 0; j < 9; ++j) {
    if (tid == 0) lc[j * 9 + j] = sqrt(lc[j * 9 + j]);
    __syncthreads();
    if (tid > j && tid < 9) lc[tid * 9 + j] /= lc[j * 9 + j];
    __syncthreads();
    if (tid > j && tid < 9) {
      double lij = lc[tid * 9 + j];
      for (int k = j + 1; k <= tid; ++k) lc[tid * 9 + k] -= lij * lc[k * 9 + j];
    }
    __syncthreads();
  }

  // Solve W * L1^T = plc (row d per lane), in place
  if (tid < 9) {
    int d = tid;
    for (int j = 0; j < 9; ++j) {
      double t = plc[d * 9 + j];
      for (int k = 0; k < j; ++k) t -= plc[d * 9 + k] * lc[j * 9 + k];
      plc[d * 9 + j] = t / lc[j * 9 + j];
    }
  }
  __syncthreads();

  // A = pc - W W^T + 1e-6 I (in place in pc)
  for (int e = tid; e < 81; e += 64) {
    int r = e / 9, c = e - 9 * (e / 9);
    double a = pc[e];
    for (int f = 0; f < 9; ++f) a -= plc[r * 9 + f] * plc[c * 9 + f];
    if (r == c) a += 1e-6;
    pc[e] = a;
  }
  __syncthreads();

  // Cholesky of pc
  for (int j = 0; j < 9; ++j) {
    if (tid == 0) pc[j * 9 + j] = sqrt(pc[j * 9 + j]);
    __syncthreads();
    if (tid > j && tid < 9) pc[tid * 9 + j] /= pc[j * 9 + j];
    __syncthreads();
    if (tid > j && tid < 9) {
      double lij = pc[tid * 9 + j];
      for (int k = j + 1; k <= tid; ++k) pc[tid * 9 + k] -= lij * pc[k * 9 + j];
    }
    __syncthreads();
  }

  if (tid == 0) {
    double sl = 0.0;
    for (int j = 0; j < 9; ++j) sl += log(pc[j * 9 + j] + 1e-8);
    *(double*)(covp + (size_t)nc * 192 + 190) = sl;  // rmi_{n,c}
  }
#undef LDM
}

// ---------------------------------------------------------------------------
// Stage 4: reduce 76 fp64 partials -> out[0] = sum / (N * NUM_CLASSES)
// ---------------------------------------------------------------------------
__global__ __launch_bounds__(64) void stage4_reduce(
    const float* __restrict__ covp, float* __restrict__ out) {
  int tid = threadIdx.x;
  double v = 0.0;
  if (tid < NBATCH * NCLS)
    v = *(const double*)(covp + (size_t)tid * 192 + 190);
  if (tid + 64 < NBATCH * NCLS)
    v += *(const double*)(covp + (size_t)(tid + 64) * 192 + 190);
#pragma unroll
  for (int o = 32; o > 0; o >>= 1) v += __shfl_down(v, o, 64);
  if (tid == 0) out[0] = (float)(v / (double)(NBATCH * NCLS));
}

// ---------------------------------------------------------------------------
extern "C" void kernel_launch(void* const* d_in, const int* in_sizes, int n_in,
                              void* d_out, int out_size, void* d_ws, size_t ws_size,
                              hipStream_t stream) {
  const float* cls  = (const float*)d_in[0];
  const int* label  = (const int*)d_in[1];
  float* out = (float*)d_out;

  float* P    = (float*)d_ws;                              // 76*29241 f32
  float* L    = P + (size_t)NBATCH * NCLS * PP2;           // 76*29241 f32
  float* covp = L + (size_t)NBATCH * NCLS * PP2;           // 2*76*192 f32

  stage1_pool<<<NBATCH * PH, 512, 0, stream>>>(cls, label, P, L);
  dim3 g2(NBATCH * NCLS, 3, ZSPLIT);
  stage2_mom<<<g2, 512, 0, stream>>>(P, L, covp);
  stage3_rmi<<<NBATCH * NCLS, 64, 0, stream>>>(covp);
  stage4_reduce<<<1, 64, 0, stream>>>(covp, out);
}